// Round 10
// baseline (1335.263 us; speedup 1.0000x reference)
//
#include <hip/hip_runtime.h>
#include <stdint.h>

#define N_NODES 100000
#define N_EDGES 3200000
#define IN_DIM  81
#define HID     64
#define LAT     32
#define BN_EPS  1e-5f
#define NCHUNK  98

__device__ __forceinline__ float bfu2f(unsigned short u) {
    return __uint_as_float(((uint32_t)u) << 16);
}
__device__ __forceinline__ float loadf(const void* p, size_t i, int fp32) {
    if (fp32) return ((const float*)p)[i];
    return bfu2f(((const unsigned short*)p)[i]);
}
__device__ __forceinline__ void load_edge(const void* ei, int f64, int e,
                                          int* s, int* d) {
    if (f64) {
        *s = (int)(((const long long*)ei)[e]);
        *d = (int)(((const long long*)ei)[(size_t)N_EDGES + e]);
    } else {
        *s = ((const int*)ei)[e];
        *d = ((const int*)ei)[(size_t)N_EDGES + e];
    }
}

// ws-too-small stamp (recognizable fp32 magnitude)
__global__ void stamp_kernel(float* out, int n, float v) {
    int i = blockIdx.x * blockDim.x + threadIdx.x;
    if (i < n) out[i] = v;
}

// flags[0]: edge int64?  flags[1+b]: per-float-input fp32? (b = 0..12)
__global__ void detect_all(const int* ei_raw,
                           const void* x, const void* W1, const void* b1,
                           const void* g1, const void* be1, const void* W2,
                           const void* b2, const void* g2, const void* be2,
                           const void* Wmu, const void* bmu, const void* Wls,
                           const void* bls, int* flags) {
    if (blockIdx.x != 0) return;
    int t = threadIdx.x;
    if (t == 13) {                 // int64 -> odd 32-bit words all zero
        int acc = 0;
        for (int k = 0; k < 128; k++) acc |= ei_raw[2 * k * 11003 + 1];
        flags[0] = (acc == 0) ? 1 : 0;
        return;
    }
    if (t >= 13) return;
    const void* bufs[13] = { x, W1, b1, g1, be1, W2, b2, g2, be2, Wmu, bmu, Wls, bls };
    const int   ns[13]   = { 512, 512, 64, 64, 64, 512, 64, 64, 64, 512, 32, 512, 32 };
    const unsigned short* u = (const unsigned short*)bufs[t];
    int n = ns[t];
    int evenZero = 0, oddNz = 0, anyNz = 0, big = 0;
    for (int i = 0; i < n; i++) {
        unsigned short s = u[i];
        if (s) anyNz = 1;
        if (i & 1) {
            if (s) oddNz = 1;
        } else {
            if ((s & 0x7F80u) == 0x7F80u) big = 1;       // inf/NaN exponent
            else if (fabsf(bfu2f(s)) > 100.0f) big = 1;  // absurd magnitude
            if (s == 0) evenZero++;
        }
    }
    int fp32 = 0;
    if (anyNz) {
        if (big) fp32 = 1;
        else if (evenZero >= n / 4 && oddNz) fp32 = 1;
    }
    flags[1 + t] = fp32;
}

__global__ void zero_misc(int* deg, float* stats) {
    int i = blockIdx.x * blockDim.x + threadIdx.x;
    if (i < N_NODES) deg[i] = 0;
    if (i < 256) stats[i] = 0.0f;
}

__global__ void convert_weights(const void* W1, const void* W2,
                                const void* Wmu, const void* Wls,
                                const void* b1, const void* b2,
                                const void* bmu, const void* bls,
                                const int* flags,
                                float* W1f, float* W2f, float* Wcatf,
                                float* b1f, float* b2f, float* bcatf) {
    int i = blockIdx.x * blockDim.x + threadIdx.x;
    if (i < IN_DIM * HID) { W1f[i] = loadf(W1, i, flags[2]); return; }
    i -= IN_DIM * HID;
    if (i < HID * HID) { W2f[i] = loadf(W2, i, flags[6]); return; }
    i -= HID * HID;
    if (i < HID * HID) {
        int k = i >> 6;
        int j = i & 63;
        if (j < LAT) Wcatf[i] = loadf(Wmu, (size_t)k * LAT + j, flags[10]);
        else         Wcatf[i] = loadf(Wls, (size_t)k * LAT + (j - LAT), flags[12]);
        return;
    }
    i -= HID * HID;
    if (i < HID) { b1f[i] = loadf(b1, i, flags[3]); return; }
    i -= HID;
    if (i < HID) { b2f[i] = loadf(b2, i, flags[7]); return; }
    i -= HID;
    if (i < HID) {
        if (i < LAT) bcatf[i] = loadf(bmu, i, flags[11]);
        else         bcatf[i] = loadf(bls, i - LAT, flags[13]);
    }
}

__global__ void deg_kernel(const void* ei_raw, const int* flags, int* deg) {
    int e = blockIdx.x * blockDim.x + threadIdx.x;
    if (e >= N_EDGES) return;
    int s, d;
    load_edge(ei_raw, flags[0], e, &s, &d);
    if (d >= 0 && d < N_NODES) atomicAdd(&deg[d], 1);
}

__global__ void dis_kernel(const int* deg, float* dis) {
    int i = blockIdx.x * blockDim.x + threadIdx.x;
    if (i < N_NODES) dis[i] = rsqrtf((float)(deg[i] + 1));
}

__global__ void scan_a(const int* deg, int* row_start, int* blk) {
    __shared__ int sd[256];
    int t = threadIdx.x;
    int bi = blockIdx.x * 1024 + t * 4;
    int v0 = (bi     < N_NODES) ? deg[bi]     : 0;
    int v1 = (bi + 1 < N_NODES) ? deg[bi + 1] : 0;
    int v2 = (bi + 2 < N_NODES) ? deg[bi + 2] : 0;
    int v3 = (bi + 3 < N_NODES) ? deg[bi + 3] : 0;
    int tsum = v0 + v1 + v2 + v3;
    sd[t] = tsum;
    __syncthreads();
    for (int off = 1; off < 256; off <<= 1) {
        int x = (t >= off) ? sd[t - off] : 0;
        __syncthreads();
        sd[t] += x;
        __syncthreads();
    }
    int excl = sd[t] - tsum;
    if (bi     < N_NODES) row_start[bi]     = excl;
    if (bi + 1 < N_NODES) row_start[bi + 1] = excl + v0;
    if (bi + 2 < N_NODES) row_start[bi + 2] = excl + v0 + v1;
    if (bi + 3 < N_NODES) row_start[bi + 3] = excl + v0 + v1 + v2;
    if (t == 255) blk[blockIdx.x] = sd[255];
}

__global__ void scan_b(int* blk) {
    __shared__ int sd[128];
    int t = threadIdx.x;
    int v = (t < NCHUNK) ? blk[t] : 0;
    sd[t] = v;
    __syncthreads();
    for (int off = 1; off < 128; off <<= 1) {
        int x = (t >= off) ? sd[t - off] : 0;
        __syncthreads();
        sd[t] += x;
        __syncthreads();
    }
    if (t < NCHUNK) blk[t] = sd[t] - v;
}

__global__ void scan_c(int* row_start, int* cursor, const int* blk) {
    int i = blockIdx.x * blockDim.x + threadIdx.x;
    if (i < N_NODES) {
        int r = row_start[i] + blk[i >> 10];
        row_start[i] = r;
        cursor[i] = r;
    }
    if (i == 0) row_start[N_NODES] = N_EDGES;
}

__global__ void fill_csr(const void* ei_raw, const int* flags, int* cursor, int* csr_src) {
    int e = blockIdx.x * blockDim.x + threadIdx.x;
    if (e >= N_EDGES) return;
    int s, d;
    load_edge(ei_raw, flags[0], e, &s, &d);
    if (d < 0 || d >= N_NODES || s < 0 || s >= N_NODES) return;
    int pos = atomicAdd(&cursor[d], 1);
    csr_src[pos] = s;
}

__global__ void gemm_l1(const void* X, const int* flags, const float* W, float* T) {
    int r = blockIdx.x * blockDim.x + threadIdx.x;
    if (r >= N_NODES) return;
    int fp = flags[1];
    size_t base = (size_t)r * IN_DIM;
    float acc[HID];
    for (int j = 0; j < HID; j++) acc[j] = 0.0f;
    for (int k = 0; k < IN_DIM; k++) {
        float a = loadf(X, base + k, fp);
        const float* wr = W + k * HID;
        for (int j = 0; j < HID; j++) acc[j] += a * wr[j];
    }
    float* To = T + (size_t)r * HID;
    for (int j = 0; j < HID; j++) To[j] = acc[j];
}

__global__ void gemm_bn(const float* F, const float* W,
                        const float* scale, const float* shift, float* T) {
    int r = blockIdx.x * blockDim.x + threadIdx.x;
    if (r >= N_NODES) return;
    const float* ar = F + (size_t)r * HID;
    float acc[HID];
    for (int j = 0; j < HID; j++) acc[j] = 0.0f;
    for (int k = 0; k < HID; k++) {
        float a = fmaxf(ar[k] * scale[k] + shift[k], 0.0f);
        const float* wr = W + k * HID;
        for (int j = 0; j < HID; j++) acc[j] += a * wr[j];
    }
    float* To = T + (size_t)r * HID;
    for (int j = 0; j < HID; j++) To[j] = acc[j];
}

// one wave per node, lane = feature
// F[n] = bias + dis[n]*( T[n]*dis[n] + sum_{src in row n} T[src]*dis[src] )
__global__ void agg_mid(const float* T, const int* row_start, const int* csr,
                        const float* dis, const float* bias, float* F) {
    int node = (blockIdx.x * blockDim.x + threadIdx.x) >> 6;
    int lane = threadIdx.x & 63;
    if (node >= N_NODES) return;
    float dn = dis[node];
    float acc = T[(size_t)node * HID + lane] * dn;
    int s0 = row_start[node];
    int s1 = row_start[node + 1];
    for (int e = s0; e < s1; e += 64) {
        int cnt = s1 - e;
        if (cnt > 64) cnt = 64;
        int src = 0;
        float dsrc = 0.0f;
        if (lane < cnt) { src = csr[e + lane]; dsrc = dis[src]; }
        for (int j = 0; j < cnt; j++) {
            int sj = __shfl(src, j);
            float dj = __shfl(dsrc, j);
            acc += T[(size_t)sj * HID + lane] * dj;
        }
    }
    F[(size_t)node * HID + lane] = bias[lane] + dn * acc;
}

// final aggregation: write fp32 to d_out (reference output dtype is float32!)
// layout: mu[100000x32] flat, then logstd[100000x32] flat
__global__ void agg_out(const float* T, const int* row_start, const int* csr,
                        const float* dis, const float* bias, float* out) {
    int node = (blockIdx.x * blockDim.x + threadIdx.x) >> 6;
    int lane = threadIdx.x & 63;
    if (node >= N_NODES) return;
    float dn = dis[node];
    float acc = T[(size_t)node * HID + lane] * dn;
    int s0 = row_start[node];
    int s1 = row_start[node + 1];
    for (int e = s0; e < s1; e += 64) {
        int cnt = s1 - e;
        if (cnt > 64) cnt = 64;
        int src = 0;
        float dsrc = 0.0f;
        if (lane < cnt) { src = csr[e + lane]; dsrc = dis[src]; }
        for (int j = 0; j < cnt; j++) {
            int sj = __shfl(src, j);
            float dj = __shfl(dsrc, j);
            acc += T[(size_t)sj * HID + lane] * dj;
        }
    }
    float res = bias[lane] + dn * acc;
    if (lane < LAT)
        out[(size_t)node * LAT + lane] = res;
    else
        out[(size_t)N_NODES * LAT + (size_t)node * LAT + (lane - LAT)] = res;
}

__global__ void stats_kernel(const float* F, float* stats) {
    int lane = threadIdx.x & 63;
    int wv = threadIdx.x >> 6;
    float s = 0.0f;
    float q = 0.0f;
    for (int r = blockIdx.x * 4 + wv; r < N_NODES; r += gridDim.x * 4) {
        float v = F[(size_t)r * HID + lane];
        s += v;
        q += v * v;
    }
    __shared__ float ls[256];
    __shared__ float lq[256];
    ls[threadIdx.x] = s;
    lq[threadIdx.x] = q;
    __syncthreads();
    if (threadIdx.x < 64) {
        s = ls[threadIdx.x] + ls[64 + threadIdx.x] + ls[128 + threadIdx.x] + ls[192 + threadIdx.x];
        q = lq[threadIdx.x] + lq[64 + threadIdx.x] + lq[128 + threadIdx.x] + lq[192 + threadIdx.x];
        atomicAdd(&stats[lane], s);
        atomicAdd(&stats[64 + lane], q);
    }
}

__global__ void finalize_bn(const float* stats, const void* g, const void* beta,
                            const int* flags, int gflag, int bflag,
                            float* scale, float* shift) {
    int j = threadIdx.x;
    if (j >= HID) return;
    float inv_n = 1.0f / (float)N_NODES;
    float mean = stats[j] * inv_n;
    float var = stats[64 + j] * inv_n - mean * mean;
    float sc = loadf(g, j, flags[gflag]) * rsqrtf(var + BN_EPS);
    scale[j] = sc;
    shift[j] = loadf(beta, j, flags[bflag]) - mean * sc;
}

extern "C" void kernel_launch(void* const* d_in, const int* in_sizes, int n_in,
                              void* d_out, int out_size, void* d_ws, size_t ws_size,
                              hipStream_t stream) {
    (void)in_sizes;
    (void)n_in;
    const void* x   = d_in[0];
    const void* ei  = d_in[1];
    const void* W1  = d_in[2];
    const void* b1  = d_in[3];
    const void* g1  = d_in[4];
    const void* be1 = d_in[5];
    const void* W2  = d_in[6];
    const void* b2  = d_in[7];
    const void* g2  = d_in[8];
    const void* be2 = d_in[9];
    const void* Wmu = d_in[10];
    const void* bmu = d_in[11];
    const void* Wls = d_in[12];
    const void* bls = d_in[13];
    float* out = (float*)d_out;   // reference output dtype = float32

    char* base = (char*)d_ws;
    size_t off = 0;
    int* csr = (int*)(base + off);
    off += (size_t)N_EDGES * 4;        off = (off + 511) & ~(size_t)511;
    float* T = (float*)(base + off);
    off += (size_t)N_NODES * HID * 4;  off = (off + 511) & ~(size_t)511;
    float* F = (float*)(base + off);
    off += (size_t)N_NODES * HID * 4;  off = (off + 511) & ~(size_t)511;
    float* dis = (float*)(base + off);
    off += (size_t)N_NODES * 4;        off = (off + 511) & ~(size_t)511;
    int* deg = (int*)(base + off);
    off += (size_t)N_NODES * 4;        off = (off + 511) & ~(size_t)511;
    int* row_start = (int*)(base + off);
    off += (size_t)(N_NODES + 1) * 4;  off = (off + 511) & ~(size_t)511;
    int* cursor = (int*)(base + off);
    off += (size_t)N_NODES * 4;        off = (off + 511) & ~(size_t)511;
    int* blk = (int*)(base + off);
    off += 1024 * 4;                   off = (off + 511) & ~(size_t)511;
    int* flags = (int*)(base + off);   // [0] edge i64, [1..13] per-input fp32
    off += 512;                        off = (off + 511) & ~(size_t)511;
    float* W1f = (float*)(base + off);
    off += (size_t)IN_DIM * HID * 4;   off = (off + 511) & ~(size_t)511;
    float* W2f = (float*)(base + off);
    off += (size_t)HID * HID * 4;      off = (off + 511) & ~(size_t)511;
    float* Wcatf = (float*)(base + off);
    off += (size_t)HID * HID * 4;      off = (off + 511) & ~(size_t)511;
    float* b1f = (float*)(base + off);
    off += HID * 4;                    off = (off + 511) & ~(size_t)511;
    float* b2f = (float*)(base + off);
    off += HID * 4;                    off = (off + 511) & ~(size_t)511;
    float* bcatf = (float*)(base + off);
    off += HID * 4;                    off = (off + 511) & ~(size_t)511;
    float* stats = (float*)(base + off);
    off += 256 * 4;                    off = (off + 511) & ~(size_t)511;
    float* scale1 = (float*)(base + off);
    off += HID * 4;                    off = (off + 511) & ~(size_t)511;
    float* shift1 = (float*)(base + off);
    off += HID * 4;                    off = (off + 511) & ~(size_t)511;
    float* scale2 = (float*)(base + off);
    off += HID * 4;                    off = (off + 511) & ~(size_t)511;
    float* shift2 = (float*)(base + off);
    off += HID * 4;

    const int BT = 256;
    int gN   = (N_NODES + BT - 1) / BT;
    int gE   = (N_EDGES + BT - 1) / BT;
    int gW   = (N_NODES * 64 + BT - 1) / BT;
    int gOut = (out_size + BT - 1) / BT;
    int gCv  = (IN_DIM * HID + 2 * HID * HID + 3 * HID + BT - 1) / BT;

    if (ws_size < off) {
        stamp_kernel<<<gOut, BT, 0, stream>>>(out, out_size, 6.8e37f);
        return;
    }

    detect_all<<<1, 64, 0, stream>>>((const int*)ei, x, W1, b1, g1, be1, W2, b2,
                                     g2, be2, Wmu, bmu, Wls, bls, flags);
    zero_misc<<<gN, BT, 0, stream>>>(deg, stats);
    convert_weights<<<gCv, BT, 0, stream>>>(W1, W2, Wmu, Wls, b1, b2, bmu, bls,
                                            flags, W1f, W2f, Wcatf, b1f, b2f, bcatf);
    deg_kernel<<<gE, BT, 0, stream>>>(ei, flags, deg);
    dis_kernel<<<gN, BT, 0, stream>>>(deg, dis);
    scan_a<<<NCHUNK, BT, 0, stream>>>(deg, row_start, blk);
    scan_b<<<1, 128, 0, stream>>>(blk);
    scan_c<<<gN, BT, 0, stream>>>(row_start, cursor, blk);
    fill_csr<<<gE, BT, 0, stream>>>(ei, flags, cursor, csr);

    // layer 1
    gemm_l1<<<gN, BT, 0, stream>>>(x, flags, W1f, T);
    agg_mid<<<gW, BT, 0, stream>>>(T, row_start, csr, dis, b1f, F);
    stats_kernel<<<256, BT, 0, stream>>>(F, stats);
    finalize_bn<<<1, 64, 0, stream>>>(stats, g1, be1, flags, 4, 5, scale1, shift1);

    // layer 2
    gemm_bn<<<gN, BT, 0, stream>>>(F, W2f, scale1, shift1, T);
    agg_mid<<<gW, BT, 0, stream>>>(T, row_start, csr, dis, b2f, F);
    stats_kernel<<<256, BT, 0, stream>>>(F, stats + 128);
    finalize_bn<<<1, 64, 0, stream>>>(stats + 128, g2, be2, flags, 8, 9, scale2, shift2);

    // layer 3 -> output (fp32)
    gemm_bn<<<gN, BT, 0, stream>>>(F, Wcatf, scale2, shift2, T);
    agg_out<<<gW, BT, 0, stream>>>(T, row_start, csr, dis, bcatf, out);
}

// Round 11
// 1013.673 us; speedup vs baseline: 1.3173x; 1.3173x over previous
//
#include <hip/hip_runtime.h>
#include <stdint.h>

#define N_NODES 100000
#define N_EDGES 3200000
#define IN_DIM  81
#define HID     64
#define LAT     32
#define BN_EPS  1e-5f
#define NBUCKET 391      /* ceil(N_NODES/256) */
#define EPB     8192     /* edges per block in bucket passes */
#define NBLK_E  391      /* ceil(N_EDGES/EPB) */

__device__ __forceinline__ float bfu2f(unsigned short u) {
    return __uint_as_float(((uint32_t)u) << 16);
}
__device__ __forceinline__ unsigned short f2bfu(float f) {
    uint32_t x = __float_as_uint(f);
    return (unsigned short)((x + 0x7FFFu + ((x >> 16) & 1u)) >> 16);
}
__device__ __forceinline__ uint32_t pack2(float a, float b) {
    return (uint32_t)f2bfu(a) | ((uint32_t)f2bfu(b) << 16);
}
__device__ __forceinline__ float loadf(const void* p, size_t i, int fp32) {
    if (fp32) return ((const float*)p)[i];
    return bfu2f(((const unsigned short*)p)[i]);
}
__device__ __forceinline__ int load_dst(const void* ei, int f64, long e) {
    if (f64) return (int)(((const long long*)ei)[(size_t)N_EDGES + e]);
    return ((const int*)ei)[(size_t)N_EDGES + e];
}
__device__ __forceinline__ int load_src(const void* ei, int f64, long e) {
    if (f64) return (int)(((const long long*)ei)[e]);
    return ((const int*)ei)[e];
}

__global__ void stamp_kernel(float* out, int n, float v) {
    int i = blockIdx.x * blockDim.x + threadIdx.x;
    if (i < n) out[i] = v;
}

// flags[0]: edge int64?  flags[1+b]: per-float-input fp32?
__global__ void detect_all(const int* ei_raw,
                           const void* x, const void* W1, const void* b1,
                           const void* g1, const void* be1, const void* W2,
                           const void* b2, const void* g2, const void* be2,
                           const void* Wmu, const void* bmu, const void* Wls,
                           const void* bls, int* flags) {
    if (blockIdx.x != 0) return;
    int t = threadIdx.x;
    if (t == 13) {
        int acc = 0;
        for (int k = 0; k < 128; k++) acc |= ei_raw[2 * k * 11003 + 1];
        flags[0] = (acc == 0) ? 1 : 0;
        return;
    }
    if (t >= 13) return;
    const void* bufs[13] = { x, W1, b1, g1, be1, W2, b2, g2, be2, Wmu, bmu, Wls, bls };
    const int   ns[13]   = { 512, 512, 64, 64, 64, 512, 64, 64, 64, 512, 32, 512, 32 };
    const unsigned short* u = (const unsigned short*)bufs[t];
    int n = ns[t];
    int evenZero = 0, oddNz = 0, anyNz = 0, big = 0;
    for (int i = 0; i < n; i++) {
        unsigned short s = u[i];
        if (s) anyNz = 1;
        if (i & 1) { if (s) oddNz = 1; }
        else {
            if ((s & 0x7F80u) == 0x7F80u) big = 1;
            else if (fabsf(bfu2f(s)) > 100.0f) big = 1;
            if (s == 0) evenZero++;
        }
    }
    int fp32 = 0;
    if (anyNz) {
        if (big) fp32 = 1;
        else if (evenZero >= n / 4 && oddNz) fp32 = 1;
    }
    flags[1 + t] = fp32;
}

// zero stats[256] and bcnt[391]; grid 2 x 256
__global__ void zero_misc(float* stats, int* bcnt) {
    int i = blockIdx.x * blockDim.x + threadIdx.x;
    if (i < 256) stats[i] = 0.0f;
    if (i < NBUCKET) bcnt[i] = 0;
}

__global__ void convert_weights(const void* W1, const void* W2,
                                const void* Wmu, const void* Wls,
                                const void* b1, const void* b2,
                                const void* bmu, const void* bls,
                                const int* flags,
                                float* W1f, float* W2f, float* Wcatf,
                                float* b1f, float* b2f, float* bcatf) {
    int i = blockIdx.x * blockDim.x + threadIdx.x;
    if (i < IN_DIM * HID) { W1f[i] = loadf(W1, i, flags[2]); return; }
    i -= IN_DIM * HID;
    if (i < HID * HID) { W2f[i] = loadf(W2, i, flags[6]); return; }
    i -= HID * HID;
    if (i < HID * HID) {
        int k = i >> 6;
        int j = i & 63;
        if (j < LAT) Wcatf[i] = loadf(Wmu, (size_t)k * LAT + j, flags[10]);
        else         Wcatf[i] = loadf(Wls, (size_t)k * LAT + (j - LAT), flags[12]);
        return;
    }
    i -= HID * HID;
    if (i < HID) { b1f[i] = loadf(b1, i, flags[3]); return; }
    i -= HID;
    if (i < HID) { b2f[i] = loadf(b2, i, flags[7]); return; }
    i -= HID;
    if (i < HID) {
        if (i < LAT) bcatf[i] = loadf(bmu, i, flags[11]);
        else         bcatf[i] = loadf(bls, i - LAT, flags[13]);
    }
}

// ---- bucketed CSR build (counting sort by dst>>8) ----
// K1: per-block LDS histogram of dst buckets -> global bucket counts
__global__ void bucket_hist(const void* ei, const int* flags, int* bcnt) {
    __shared__ int h[NBUCKET];
    for (int i = threadIdx.x; i < NBUCKET; i += 256) h[i] = 0;
    __syncthreads();
    int f64 = flags[0];
    long e0 = (long)blockIdx.x * EPB;
    for (int i = 0; i < EPB / 256; i++) {
        long e = e0 + i * 256 + threadIdx.x;
        if (e < N_EDGES) atomicAdd(&h[load_dst(ei, f64, e) >> 8], 1);
    }
    __syncthreads();
    for (int i = threadIdx.x; i < NBUCKET; i += 256)
        if (h[i]) atomicAdd(&bcnt[i], h[i]);
}

// K2: exclusive scan of 391 bucket counts (512-slot LDS scan, 256 threads)
__global__ void bucket_scan(const int* bcnt, int* bbase, int* bcur, int* row_start) {
    __shared__ int sd[512];
    int t = threadIdx.x;
    int v0 = (t < NBUCKET) ? bcnt[t] : 0;
    int v1 = (t + 256 < NBUCKET) ? bcnt[t + 256] : 0;
    sd[t] = v0;
    sd[t + 256] = v1;
    __syncthreads();
    for (int off = 1; off < 256; off <<= 1) {       // scan lower half
        int x = (t >= off) ? sd[t - off] : 0;
        __syncthreads();
        sd[t] += x;
        __syncthreads();
    }
    int low_total = sd[255];
    for (int off = 1; off < 256; off <<= 1) {       // scan upper half
        int x = (t >= off) ? sd[256 + t - off] : 0;
        __syncthreads();
        sd[256 + t] += x;
        __syncthreads();
    }
    if (t < NBUCKET) {
        int excl = sd[t] - v0;
        bbase[t] = excl;
        bcur[t] = excl;
    }
    int j = 256 + t;
    if (j < NBUCKET) {
        int excl = sd[j] + low_total - v1;
        bbase[j] = excl;
        bcur[j] = excl;
    }
    if (t == 0) {
        bbase[NBUCKET] = N_EDGES;
        row_start[N_NODES] = N_EDGES;
    }
}

// K3: scatter edges into bucket-contiguous staging; record = (dst&255)<<17 | src
__global__ void bucket_scatter(const void* ei, const int* flags, int* bcur,
                               int* staged) {
    __shared__ int h[NBUCKET];
    __shared__ int lbase[NBUCKET];
    __shared__ int cnt[NBUCKET];
    for (int i = threadIdx.x; i < NBUCKET; i += 256) { h[i] = 0; cnt[i] = 0; }
    __syncthreads();
    int f64 = flags[0];
    long e0 = (long)blockIdx.x * EPB;
    for (int i = 0; i < EPB / 256; i++) {
        long e = e0 + i * 256 + threadIdx.x;
        if (e < N_EDGES) atomicAdd(&h[load_dst(ei, f64, e) >> 8], 1);
    }
    __syncthreads();
    for (int i = threadIdx.x; i < NBUCKET; i += 256)
        lbase[i] = h[i] ? atomicAdd(&bcur[i], h[i]) : 0;
    __syncthreads();
    for (int i = 0; i < EPB / 256; i++) {
        long e = e0 + i * 256 + threadIdx.x;
        if (e < N_EDGES) {
            int d = load_dst(ei, f64, e);
            int s = load_src(ei, f64, e);
            int b = d >> 8;
            int off = atomicAdd(&cnt[b], 1);
            staged[lbase[b] + off] = ((d & 255) << 17) | s;
        }
    }
}

// K4: one block per bucket: LDS deg/scan/cursors -> dis, row_start, csr
__global__ void csr_build(const int* bbase, const int* staged, float* dis,
                          int* row_start, int* csr) {
    int b = blockIdx.x;
    int t = threadIdx.x;
    int n0 = b << 8;
    int nn = N_NODES - n0;
    if (nn > 256) nn = 256;
    int e0 = bbase[b];
    int e1 = bbase[b + 1];
    __shared__ int ldeg[256];
    __shared__ int lcur[256];
    __shared__ int sd[256];
    ldeg[t] = 0;
    __syncthreads();
    for (int i = e0 + t; i < e1; i += 256)
        atomicAdd(&ldeg[staged[i] >> 17], 1);
    __syncthreads();
    int v = ldeg[t];
    sd[t] = v;
    __syncthreads();
    for (int off = 1; off < 256; off <<= 1) {
        int x = (t >= off) ? sd[t - off] : 0;
        __syncthreads();
        sd[t] += x;
        __syncthreads();
    }
    int excl = sd[t] - v;
    if (t < nn) {
        dis[n0 + t] = rsqrtf((float)(v + 1));
        row_start[n0 + t] = e0 + excl;
    }
    lcur[t] = e0 + excl;
    __syncthreads();
    for (int i = e0 + t; i < e1; i += 256) {
        int rec = staged[i];
        int pos = atomicAdd(&lcur[rec >> 17], 1);
        csr[pos] = rec & 0x1FFFF;
    }
}

// ---- dense layers (T stored bf16, fp32 accumulate) ----
__global__ void gemm_l1(const void* X, const int* flags, const float* W,
                        unsigned short* T) {
    int r = blockIdx.x * blockDim.x + threadIdx.x;
    if (r >= N_NODES) return;
    int fp = flags[1];
    size_t base = (size_t)r * IN_DIM;
    float acc[HID];
    for (int j = 0; j < HID; j++) acc[j] = 0.0f;
    for (int k = 0; k < IN_DIM; k++) {
        float a = loadf(X, base + k, fp);
        const float* wr = W + k * HID;
        for (int j = 0; j < HID; j++) acc[j] += a * wr[j];
    }
    uint32_t* To = (uint32_t*)(T + (size_t)r * HID);
    for (int j = 0; j < HID / 2; j++) To[j] = pack2(acc[2 * j], acc[2 * j + 1]);
}

__global__ void gemm_bn(const float* F, const float* W,
                        const float* scale, const float* shift, unsigned short* T) {
    int r = blockIdx.x * blockDim.x + threadIdx.x;
    if (r >= N_NODES) return;
    const float* ar = F + (size_t)r * HID;
    float acc[HID];
    for (int j = 0; j < HID; j++) acc[j] = 0.0f;
    for (int k = 0; k < HID; k++) {
        float a = fmaxf(ar[k] * scale[k] + shift[k], 0.0f);
        const float* wr = W + k * HID;
        for (int j = 0; j < HID; j++) acc[j] += a * wr[j];
    }
    uint32_t* To = (uint32_t*)(T + (size_t)r * HID);
    for (int j = 0; j < HID / 2; j++) To[j] = pack2(acc[2 * j], acc[2 * j + 1]);
}

// one wave per node, lane = feature; T bf16 gather, fp32 accumulate
__global__ void agg_mid(const unsigned short* T, const int* row_start, const int* csr,
                        const float* dis, const float* bias, float* F) {
    int node = (blockIdx.x * blockDim.x + threadIdx.x) >> 6;
    int lane = threadIdx.x & 63;
    if (node >= N_NODES) return;
    float dn = dis[node];
    float acc = bfu2f(T[(size_t)node * HID + lane]) * dn;
    int s0 = row_start[node];
    int s1 = row_start[node + 1];
    for (int e = s0; e < s1; e += 64) {
        int cnt = s1 - e;
        if (cnt > 64) cnt = 64;
        int src = 0;
        float dsrc = 0.0f;
        if (lane < cnt) { src = csr[e + lane]; dsrc = dis[src]; }
        for (int j = 0; j < cnt; j++) {
            int sj = __shfl(src, j);
            float dj = __shfl(dsrc, j);
            acc += bfu2f(T[(size_t)sj * HID + lane]) * dj;
        }
    }
    F[(size_t)node * HID + lane] = bias[lane] + dn * acc;
}

__global__ void agg_out(const unsigned short* T, const int* row_start, const int* csr,
                        const float* dis, const float* bias, float* out) {
    int node = (blockIdx.x * blockDim.x + threadIdx.x) >> 6;
    int lane = threadIdx.x & 63;
    if (node >= N_NODES) return;
    float dn = dis[node];
    float acc = bfu2f(T[(size_t)node * HID + lane]) * dn;
    int s0 = row_start[node];
    int s1 = row_start[node + 1];
    for (int e = s0; e < s1; e += 64) {
        int cnt = s1 - e;
        if (cnt > 64) cnt = 64;
        int src = 0;
        float dsrc = 0.0f;
        if (lane < cnt) { src = csr[e + lane]; dsrc = dis[src]; }
        for (int j = 0; j < cnt; j++) {
            int sj = __shfl(src, j);
            float dj = __shfl(dsrc, j);
            acc += bfu2f(T[(size_t)sj * HID + lane]) * dj;
        }
    }
    float res = bias[lane] + dn * acc;
    if (lane < LAT)
        out[(size_t)node * LAT + lane] = res;
    else
        out[(size_t)N_NODES * LAT + (size_t)node * LAT + (lane - LAT)] = res;
}

__global__ void stats_kernel(const float* F, float* stats) {
    int lane = threadIdx.x & 63;
    int wv = threadIdx.x >> 6;
    float s = 0.0f;
    float q = 0.0f;
    for (int r = blockIdx.x * 4 + wv; r < N_NODES; r += gridDim.x * 4) {
        float v = F[(size_t)r * HID + lane];
        s += v;
        q += v * v;
    }
    __shared__ float ls[256];
    __shared__ float lq[256];
    ls[threadIdx.x] = s;
    lq[threadIdx.x] = q;
    __syncthreads();
    if (threadIdx.x < 64) {
        s = ls[threadIdx.x] + ls[64 + threadIdx.x] + ls[128 + threadIdx.x] + ls[192 + threadIdx.x];
        q = lq[threadIdx.x] + lq[64 + threadIdx.x] + lq[128 + threadIdx.x] + lq[192 + threadIdx.x];
        atomicAdd(&stats[lane], s);
        atomicAdd(&stats[64 + lane], q);
    }
}

__global__ void finalize_bn(const float* stats, const void* g, const void* beta,
                            const int* flags, int gflag, int bflag,
                            float* scale, float* shift) {
    int j = threadIdx.x;
    if (j >= HID) return;
    float inv_n = 1.0f / (float)N_NODES;
    float mean = stats[j] * inv_n;
    float var = stats[64 + j] * inv_n - mean * mean;
    float sc = loadf(g, j, flags[gflag]) * rsqrtf(var + BN_EPS);
    scale[j] = sc;
    shift[j] = loadf(beta, j, flags[bflag]) - mean * sc;
}

extern "C" void kernel_launch(void* const* d_in, const int* in_sizes, int n_in,
                              void* d_out, int out_size, void* d_ws, size_t ws_size,
                              hipStream_t stream) {
    (void)in_sizes;
    (void)n_in;
    const void* x   = d_in[0];
    const void* ei  = d_in[1];
    const void* W1  = d_in[2];
    const void* b1  = d_in[3];
    const void* g1  = d_in[4];
    const void* be1 = d_in[5];
    const void* W2  = d_in[6];
    const void* b2  = d_in[7];
    const void* g2  = d_in[8];
    const void* be2 = d_in[9];
    const void* Wmu = d_in[10];
    const void* bmu = d_in[11];
    const void* Wls = d_in[12];
    const void* bls = d_in[13];
    float* out = (float*)d_out;

    char* base = (char*)d_ws;
    size_t off = 0;
    int* staged = (int*)(base + off);
    off += (size_t)N_EDGES * 4;        off = (off + 511) & ~(size_t)511;
    int* csr = (int*)(base + off);
    off += (size_t)N_EDGES * 4;        off = (off + 511) & ~(size_t)511;
    unsigned short* T = (unsigned short*)(base + off);
    off += (size_t)N_NODES * HID * 2;  off = (off + 511) & ~(size_t)511;
    float* F = (float*)(base + off);
    off += (size_t)N_NODES * HID * 4;  off = (off + 511) & ~(size_t)511;
    float* dis = (float*)(base + off);
    off += (size_t)N_NODES * 4;        off = (off + 511) & ~(size_t)511;
    int* row_start = (int*)(base + off);
    off += (size_t)(N_NODES + 1) * 4;  off = (off + 511) & ~(size_t)511;
    int* bcnt = (int*)(base + off);
    off += NBUCKET * 4;                off = (off + 511) & ~(size_t)511;
    int* bbase = (int*)(base + off);
    off += (NBUCKET + 1) * 4;          off = (off + 511) & ~(size_t)511;
    int* bcur = (int*)(base + off);
    off += NBUCKET * 4;                off = (off + 511) & ~(size_t)511;
    int* flags = (int*)(base + off);
    off += 512;                        off = (off + 511) & ~(size_t)511;
    float* W1f = (float*)(base + off);
    off += (size_t)IN_DIM * HID * 4;   off = (off + 511) & ~(size_t)511;
    float* W2f = (float*)(base + off);
    off += (size_t)HID * HID * 4;      off = (off + 511) & ~(size_t)511;
    float* Wcatf = (float*)(base + off);
    off += (size_t)HID * HID * 4;      off = (off + 511) & ~(size_t)511;
    float* b1f = (float*)(base + off);
    off += HID * 4;                    off = (off + 511) & ~(size_t)511;
    float* b2f = (float*)(base + off);
    off += HID * 4;                    off = (off + 511) & ~(size_t)511;
    float* bcatf = (float*)(base + off);
    off += HID * 4;                    off = (off + 511) & ~(size_t)511;
    float* stats = (float*)(base + off);
    off += 256 * 4;                    off = (off + 511) & ~(size_t)511;
    float* scale1 = (float*)(base + off);
    off += HID * 4;                    off = (off + 511) & ~(size_t)511;
    float* shift1 = (float*)(base + off);
    off += HID * 4;                    off = (off + 511) & ~(size_t)511;
    float* scale2 = (float*)(base + off);
    off += HID * 4;                    off = (off + 511) & ~(size_t)511;
    float* shift2 = (float*)(base + off);
    off += HID * 4;

    const int BT = 256;
    int gN   = (N_NODES + BT - 1) / BT;          // 391
    int gW   = (N_NODES * 64 + BT - 1) / BT;     // 25000
    int gOut = (out_size + BT - 1) / BT;
    int gCv  = (IN_DIM * HID + 2 * HID * HID + 3 * HID + BT - 1) / BT;

    if (ws_size < off) {
        stamp_kernel<<<gOut, BT, 0, stream>>>(out, out_size, 6.8e37f);
        return;
    }

    detect_all<<<1, 64, 0, stream>>>((const int*)ei, x, W1, b1, g1, be1, W2, b2,
                                     g2, be2, Wmu, bmu, Wls, bls, flags);
    zero_misc<<<2, BT, 0, stream>>>(stats, bcnt);
    convert_weights<<<gCv, BT, 0, stream>>>(W1, W2, Wmu, Wls, b1, b2, bmu, bls,
                                            flags, W1f, W2f, Wcatf, b1f, b2f, bcatf);

    // bucketed CSR build
    bucket_hist<<<NBLK_E, BT, 0, stream>>>(ei, flags, bcnt);
    bucket_scan<<<1, BT, 0, stream>>>(bcnt, bbase, bcur, row_start);
    bucket_scatter<<<NBLK_E, BT, 0, stream>>>(ei, flags, bcur, staged);
    csr_build<<<NBUCKET, BT, 0, stream>>>(bbase, staged, dis, row_start, csr);

    // layer 1
    gemm_l1<<<gN, BT, 0, stream>>>(x, flags, W1f, T);
    agg_mid<<<gW, BT, 0, stream>>>(T, row_start, csr, dis, b1f, F);
    stats_kernel<<<256, BT, 0, stream>>>(F, stats);
    finalize_bn<<<1, 64, 0, stream>>>(stats, g1, be1, flags, 4, 5, scale1, shift1);

    // layer 2
    gemm_bn<<<gN, BT, 0, stream>>>(F, W2f, scale1, shift1, T);
    agg_mid<<<gW, BT, 0, stream>>>(T, row_start, csr, dis, b2f, F);
    stats_kernel<<<256, BT, 0, stream>>>(F, stats + 128);
    finalize_bn<<<1, 64, 0, stream>>>(stats + 128, g2, be2, flags, 8, 9, scale2, shift2);

    // layer 3 -> output (fp32)
    gemm_bn<<<gN, BT, 0, stream>>>(F, Wcatf, scale2, shift2, T);
    agg_out<<<gW, BT, 0, stream>>>(T, row_start, csr, dis, bcatf, out);
}